// Round 11
// baseline (2671.480 us; speedup 1.0000x reference)
//
#include <hip/hip_runtime.h>
#include <hip/hip_bf16.h>

#define SEQ_LEN 256
#define HIDDEN  2048
#define CLASSES 10
#define BATCH   128
#define NWG     256
#define WG_THREADS 512
#define STEPS   (SEQ_LEN - 1)
#define KTILES  64            // per K-half: 1024 / 16
#define PF      16            // A-prefetch depth (ktiles ahead)
#define LDS_WH  131072
#define RED_OFF    LDS_WH                  // K-half reduction: 256 slots * 72 B
#define RED_STRIDE 72
#define LDS_ALL    (LDS_WH + 18432)

typedef __attribute__((ext_vector_type(8)))  short  bf16x8;
typedef __attribute__((ext_vector_type(8)))  unsigned short u16x8;
typedef __attribute__((ext_vector_type(16))) float  f32x16;
typedef __attribute__((ext_vector_type(4)))  unsigned int u32x4;

// ---- workspace layout (bytes) ----
#define WHP_OFF  0
#define HB_OFF   33554432UL                    // 4 x 512 KB rotating h buffers, layout h[kblk][row][u]
#define HF_OFF   (HB_OFF + 4UL * 524288UL)     // fp32 h_final [128][2048]
#define BAR_OFF  (HF_OFF + 1048576UL)
// bar layout (dwords): as R1 (contention-free tree, monotonic phases).
// Session lessons: R2 flat all-poll barrier = coherence-point contention.
// R4: don't perturb the MFMA/load schedule for ILP. R5: agent-scope stores
// merge into full lines ONLY when lane-contiguous per instruction. R6:
// all-to-all consumption -> flags can't beat the barrier. R7: 128-VGPR breg
// = spills. R8: tail-split ~4% win. R9: halving LDS B-reads = FLAT (LDS not
// binding). R10: direct coalesced h-write (hstage deleted) ~neutral, kept.
// Remaining budget/step: ~3.7us cross-XCD L2 ingest floor + ~1.5-2us barrier
// + tail + latency. R11: symmetric split-finish — kh=0 finishes quads a=0,1;
// kh=1 finishes a=2,3; each ships the other half (disjoint 32B halves of the
// same 72B slot), so the gate/exp/store tail runs on all 8 waves instead of 4.

__device__ __forceinline__ unsigned short f2bf(float f) {
    unsigned int u = __float_as_uint(f);
    return (unsigned short)((u + 0x7FFFu + ((u >> 16) & 1u)) >> 16);
}
__device__ __forceinline__ float sigm(float z)  { return 1.0f / (1.0f + __expf(-z)); }
__device__ __forceinline__ float tanh_f(float z){ return 2.0f / (1.0f + __expf(-2.0f * z)) - 1.0f; }

__device__ __forceinline__ unsigned int aload(const unsigned int* p) {
    return __hip_atomic_load(p, __ATOMIC_RELAXED, __HIP_MEMORY_SCOPE_AGENT);
}
__device__ __forceinline__ void astore(unsigned int* p, unsigned int v) {
    __hip_atomic_store(p, v, __ATOMIC_RELAXED, __HIP_MEMORY_SCOPE_AGENT);
}
__device__ __forceinline__ void astore_s(unsigned short* p, unsigned short v) {
    __hip_atomic_store(p, v, __ATOMIC_RELAXED, __HIP_MEMORY_SCOPE_AGENT);
}

// Pack Wh [2048][8192] fp32 -> bf16 32x32x16 B-fragments.
// whp chunk = W*8192 + kh*4096 + kt*64 + lane (16 B units).
// Fragment: col = lane&31 -> (gate = col>>3, u = col&7), k = kh*1024 + kt*16
// + (lane>>5)*8 + j.  (k-octet convention cancels between A and B.)
__global__ void lstm_pack_kernel(const float* __restrict__ Wh,
                                 unsigned short* __restrict__ whp,
                                 unsigned short* __restrict__ hbufs,
                                 unsigned int* __restrict__ bar) {
    int chunk = blockIdx.x * 256 + threadIdx.x;     // 2,097,152 chunks total
    int lane = chunk & 63;
    int kt   = (chunk >> 6) & 63;
    int kh   = (chunk >> 12) & 1;
    int W    = chunk >> 13;
    int c    = lane & 31;
    int oct  = lane >> 5;
    int gate = c >> 3, u = c & 7;
    int n    = gate * 2048 + W * 8 + u;
    int k0   = kh * 1024 + kt * 16 + oct * 8;
    u16x8 frag;
    #pragma unroll
    for (int j = 0; j < 8; ++j)
        frag[j] = f2bf(Wh[(size_t)(k0 + j) * 8192 + n]);
    ((u16x8*)whp)[chunk] = frag;

    if (chunk < 32768) ((u32x4*)hbufs)[chunk] = (u32x4){0, 0, 0, 0};   // buf0: h(0)=0
    if (chunk < 2048) bar[chunk] = 0u;                                 // barrier words
}

// Contention-free monotonic tree barrier (phase = t+1, never reset). As R1.
__device__ __forceinline__ void grid_barrier(unsigned int* bar, unsigned int phase,
                                             bool do_inv, int W) {
    __syncthreads();   // drain h stores to the coherence point
    if (threadIdx.x < 64) {
        const int lane = threadIdx.x;
        if (lane == 0) astore(&bar[W], phase);                 // arrival
        if (W < 8) {
            unsigned int* sl = &bar[W * 32 + (lane & 31)];
            while (!__all((int)(aload(sl) >= phase)))
                __builtin_amdgcn_s_sleep(1);
            if (lane == 0) astore(&bar[512 + 16 * W], phase);  // done[W]
            if (W == 0) {
                unsigned int* dn = &bar[512 + 16 * (lane & 7)];
                while (!__all((int)(aload(dn) >= phase)))
                    __builtin_amdgcn_s_sleep(1);
                if (lane < 32) astore(&bar[1024 + 16 * lane], phase);  // broadcast
            }
        }
        if (lane == 0 && W != 0) {
            unsigned int* rl = &bar[1024 + 16 * (W & 31)];
            while (aload(rl) < phase)
                __builtin_amdgcn_s_sleep(1);
        }
        if (do_inv)
            __builtin_amdgcn_fence(__ATOMIC_ACQUIRE, "agent");   // buffer_inv (L1+L2)
    }
    __syncthreads();
}

__global__ __launch_bounds__(WG_THREADS, 2) void lstm_persist(
    const float* __restrict__ x,  const float* __restrict__ Wx,
    const float* __restrict__ b,  const float* __restrict__ Wph,
    const float* __restrict__ bp, const unsigned short* __restrict__ whp,
    unsigned short* hbufs, float* hfin,
    unsigned int* bar, float* out)
{
    extern __shared__ char lds[];
    const int tid = threadIdx.x;
    const int W   = blockIdx.x;

    // stage this WG's Wh slice (128 KB) into LDS (linear copy; layout matches pack)
    {
        const u32x4* src = (const u32x4*)whp + (size_t)W * 8192;
        u32x4* dst = (u32x4*)lds;
        for (int i = tid; i < 8192; i += WG_THREADS) dst[i] = src[i];
    }
    __syncthreads();

    const int lane = tid & 63;
    const int wv   = tid >> 6;
    const int wv2  = wv & 3;            // M-tile: rows 32*wv2 .. +31
    const int kh   = wv >> 2;           // K-half: k in [kh*1024, kh*1024+1024)
    const int l31  = lane & 31;
    const int oct  = lane >> 5;         // k-octet within fragment
    const int u    = lane & 7;          // hidden unit within slice
    const int gamma= (lane >> 3) & 3;   // gate index of this lane's column

    // gate-wise Wx/bias scalars for this lane's unit (INPUT_DIM = 1)
    const int nbase = W * 8 + u;
    float wxg[4], bbg[4];
    #pragma unroll
    for (int g = 0; g < 4; ++g) {
        wxg[g] = Wx[g * 2048 + nbase];
        bbg[g] = b[g * 2048 + nbase];
    }

    // A-fragment (32x32x16): row = lane&31 (within M-tile), k-octet = oct.
    // h layout h[kblk][row][8]: x8-index = (kh*128 + kt*2 + oct)*128 +
    // 32*wv2 + (lane&31); per-kt stride 256.
    const int abase = kh * 16384 + oct * 128 + 32 * wv2 + l31;
    // B-fragment LDS base: (kh*64 + kt)*1024 + lane*16 bytes
    const char* lpB0 = lds + kh * 65536 + lane * 16;

    char* redp = lds + RED_OFF + (size_t)(wv2 * 64 + lane) * RED_STRIDE;

    const int g0 = gamma & 1, g1 = (gamma >> 1) & 1;
    // this wave finishes quads a = 2*kh + al, al=0,1 (rows 16*kh + 8*al + ...)
    float c_state[2] = {0.f, 0.f};

    for (int t = 0; t < STEPS; ++t) {
        unsigned short* hcur  = hbufs + (size_t)(t & 3) * 262144;        // elements
        unsigned short* hnext = hbufs + (size_t)((t + 1) & 3) * 262144;
        const bf16x8* hc8 = (const bf16x8*)hcur;

        // xv preload for this wave's 2 quads
        float xva[2];
        #pragma unroll
        for (int al = 0; al < 2; ++al) {
            int row = 32 * wv2 + 16 * kh + 8 * al + gamma + 4 * oct;
            xva[al] = x[row * SEQ_LEN + t];
        }

        // 16-deep rotating register prefetch of A fragments
        bf16x8 a_pf[PF];
        #pragma unroll
        for (int i = 0; i < PF; ++i)
            a_pf[i] = hc8[abase + i * 256];

        f32x16 acc = {0.f};
        // phase A (kt 0..47): prefetch kt+PF always valid (tail-split, R8)
        #pragma unroll 16
        for (int kt = 0; kt < KTILES - PF; ++kt) {
            bf16x8 a_cur = a_pf[kt & (PF - 1)];
            a_pf[kt & (PF - 1)] = hc8[abase + (kt + PF) * 256];
            bf16x8 bb = *(const bf16x8*)(lpB0 + kt * 1024);
            acc = __builtin_amdgcn_mfma_f32_32x32x16_bf16(a_cur, bb, acc, 0, 0, 0);
        }
        // phase B (kt 48..63): consume a_pf, no prefetch
        #pragma unroll
        for (int i = 0; i < PF; ++i) {
            bf16x8 bb = *(const bf16x8*)(lpB0 + ((KTILES - PF) + i) * 1024);
            acc = __builtin_amdgcn_mfma_f32_32x32x16_bf16(a_pf[i], bb, acc, 0, 0, 0);
        }

        // ---- symmetric K-half exchange ----
        // regs 0..7 = quads a=0,1 (finished by kh=0); regs 8..15 = a=2,3
        // (finished by kh=1). Ship the half I don't finish; static indices via
        // wave-uniform selects (rule #20: no dynamic ext_vector indexing).
        float qsend[8], qmine[8];
        #pragma unroll
        for (int j = 0; j < 8; ++j) {
            qsend[j] = kh ? acc[j] : acc[8 + j];
            qmine[j] = kh ? acc[8 + j] : acc[j];
        }
        // slot halves: bytes [0,32) = data needed by kh=0; [32,64) = by kh=1
        {
            char* wr = redp + (kh ? 0 : 32);
            #pragma unroll
            for (int j = 0; j < 4; ++j) {
                float2 v; v.x = qsend[2 * j]; v.y = qsend[2 * j + 1];
                *(float2*)(wr + 8 * j) = v;
            }
        }
        __syncthreads();
        {
            const char* rd = redp + (kh ? 32 : 0);
            #pragma unroll
            for (int j = 0; j < 4; ++j) {
                float2 v = *(const float2*)(rd + 8 * j);
                qmine[2 * j] += v.x; qmine[2 * j + 1] += v.y;
            }
        }

        const bool last = (t == STEPS - 1);
        // gate math + direct h-write for this wave's 2 quads (all 8 waves).
        // C/D layout: col = lane&31, row = (reg&3) + 8*(reg>>2) + 4*oct;
        // xor-gather puts reg 4a+gamma in lane gamma of each 8-group.
        #pragma unroll
        for (int al = 0; al < 2; ++al) {
            float q0 = qmine[4 * al + 0], q1 = qmine[4 * al + 1];
            float q2 = qmine[4 * al + 2], q3 = qmine[4 * al + 3];
            float s1  = g0 ? (g1 ? q2 : q0) : (g1 ? q3 : q1);   // reg 4a+(γ^1)
            float s2  = g1 ? (g0 ? q1 : q0) : (g0 ? q3 : q2);   // reg 4a+(γ^2)
            float s3  = g1 ? (g0 ? q0 : q1) : (g0 ? q2 : q3);   // reg 4a+(γ^3)
            float own = g1 ? (g0 ? q3 : q2) : (g0 ? q1 : q0);   // reg 4a+γ
            float r1 = __shfl_xor(s1, 8, 64);
            float r2 = __shfl_xor(s2, 16, 64);
            float r3 = __shfl_xor(s3, 24, 64);
            float zg = g1 ? (g0 ? r3 : r2) : (g0 ? r1 : own);
            float zi = g1 ? (g0 ? r2 : r3) : (g0 ? own : r1);
            float zf = g1 ? (g0 ? r1 : own) : (g0 ? r3 : r2);
            float zo = g1 ? (g0 ? own : r1) : (g0 ? r2 : r3);
            zg += xva[al] * wxg[0] + bbg[0];
            zi += xva[al] * wxg[1] + bbg[1];
            zf += xva[al] * wxg[2] + bbg[2];
            zo += xva[al] * wxg[3] + bbg[3];
            float cn = tanh_f(zg) * sigm(zi) + c_state[al] * sigm(zf);
            c_state[al] = cn;
            float h = tanh_f(cn) * sigm(zo);
            int row = 32 * wv2 + 16 * kh + 8 * al + gamma + 4 * oct;
            // per (al) store: 64 lanes cover (gamma+4oct)*16 + u*2 = bytes
            // 0..127 -> 2 full 64B lines of the W-block (R5-safe).
            astore_s(&hnext[W * 1024 + row * 8 + u], f2bf(h));
            if (last)
                __hip_atomic_store(&hfin[row * HIDDEN + W * 8 + u], h,
                                   __ATOMIC_RELAXED, __HIP_MEMORY_SCOPE_AGENT);
        }
        // stores drain under the barrier's first __syncthreads, then arrival.
        // inv every 4th barrier (stale L2 age <= 4 with the 4-buffer rotation);
        // t==254 (phase 2) also covers the hfin handoff to the cached epilogue.
        grid_barrier(bar, (unsigned int)(t + 1), (t & 3) == 2 || last, W);
    }

    // ---- classifier + softmax epilogue: WG b handles batch row b ----
    if (W < BATCH) {
        float part[CLASSES];
        #pragma unroll
        for (int c = 0; c < CLASSES; ++c) part[c] = 0.f;
        for (int k = tid; k < HIDDEN; k += WG_THREADS) {
            float hv = hfin[W * HIDDEN + k];
            #pragma unroll
            for (int c = 0; c < CLASSES; ++c) part[c] += hv * Wph[k * CLASSES + c];
        }
        #pragma unroll
        for (int c = 0; c < CLASSES; ++c)
            for (int off = 32; off > 0; off >>= 1)
                part[c] += __shfl_xor(part[c], off, 64);
        float* red = (float*)(lds + RED_OFF);
        __syncthreads();
        const int wvq = tid >> 6;
        if ((tid & 63) == 0)
            for (int c = 0; c < CLASSES; ++c) red[wvq * CLASSES + c] = part[c];
        __syncthreads();
        if (tid == 0) {
            float lg[CLASSES];
            for (int c = 0; c < CLASSES; ++c) {
                float sm = bp[c];
                for (int w8 = 0; w8 < 8; ++w8) sm += red[w8 * CLASSES + c];
                lg[c] = sm;
            }
            float mx = lg[0];
            for (int c = 1; c < CLASSES; ++c) mx = fmaxf(mx, lg[c]);
            float se = 0.f;
            for (int c = 0; c < CLASSES; ++c) { lg[c] = __expf(lg[c] - mx); se += lg[c]; }
            float inv = 1.0f / se;
            for (int c = 0; c < CLASSES; ++c) out[W * CLASSES + c] = lg[c] * inv;
        }
    }
}

extern "C" void kernel_launch(void* const* d_in, const int* in_sizes, int n_in,
                              void* d_out, int out_size, void* d_ws, size_t ws_size,
                              hipStream_t stream) {
    const float* x   = (const float*)d_in[0];
    const float* Wx  = (const float*)d_in[1];
    const float* Wh  = (const float*)d_in[2];
    const float* b   = (const float*)d_in[3];
    const float* Wph = (const float*)d_in[4];
    const float* bp  = (const float*)d_in[5];
    float* out = (float*)d_out;

    char* ws = (char*)d_ws;
    unsigned short* whp  = (unsigned short*)(ws + WHP_OFF);
    unsigned short* hbufs= (unsigned short*)(ws + HB_OFF);
    float*          hfin = (float*)(ws + HF_OFF);
    unsigned int*   bar  = (unsigned int*)(ws + BAR_OFF);

    hipFuncSetAttribute((const void*)lstm_persist,
                        hipFuncAttributeMaxDynamicSharedMemorySize, LDS_ALL);

    lstm_pack_kernel<<<8192, 256, 0, stream>>>(Wh, whp, hbufs, bar);
    lstm_persist<<<NWG, WG_THREADS, LDS_ALL, stream>>>(x, Wx, b, Wph, bp,
                                                       whp, hbufs, hfin, bar, out);
}

// Round 13
// 2448.285 us; speedup vs baseline: 1.0912x; 1.0912x over previous
//
#include <hip/hip_runtime.h>
#include <hip/hip_bf16.h>

#define SEQ_LEN 256
#define HIDDEN  2048
#define CLASSES 10
#define BATCH   128
#define NWG     256
#define WG_THREADS 512
#define STEPS   (SEQ_LEN - 1)
#define KTILES  64            // per K-half: 1024 / 16
#define PF      16            // A-prefetch depth (ktiles ahead)
#define LDS_WH  131072
#define RED_OFF    LDS_WH                  // K-half reduction: 256 slots * 72 B
#define RED_STRIDE 72
#define LDS_ALL    (LDS_WH + 18432)

typedef __attribute__((ext_vector_type(8)))  short  bf16x8;
typedef __attribute__((ext_vector_type(8)))  unsigned short u16x8;
typedef __attribute__((ext_vector_type(16))) float  f32x16;
typedef __attribute__((ext_vector_type(4)))  unsigned int u32x4;

// ---- workspace layout (bytes) ----
#define WHP_OFF  0
#define HB_OFF   33554432UL                    // 4 x 512 KB rotating h buffers, layout h[kblk][row][u]
#define HF_OFF   (HB_OFF + 4UL * 524288UL)     // fp32 h_final [128][2048]
#define BAR_OFF  (HF_OFF + 1048576UL)
// bar layout (dwords): as R1 (contention-free tree, monotonic phases).
// FINAL (R10 structure, session best bench 2418us). Session lessons:
// R2 flat all-poll barrier = coherence-point contention. R4/R11: don't
// redistribute per-step work — step time is set by ingest+barrier, not by
// which wave does gate math. R5: agent-scope stores merge into full lines
// ONLY when lane-contiguous per instruction. R6: all-to-all consumption ->
// producer flags can't beat the barrier. R7: 128-VGPR breg = spills.
// R8: tail-split ~4% win. R9: halving LDS B-reads = FLAT (LDS not binding).
// R10: direct coalesced h-write (hstage deleted), best bench. Plateau:
// ~3.7us/step cross-XCD h-ingest floor + ~1.5-2us barrier + skew; no PMC
// pipe saturated (MfmaUtil ~19, VALUBusy ~16, HBM 3%).

__device__ __forceinline__ unsigned short f2bf(float f) {
    unsigned int u = __float_as_uint(f);
    return (unsigned short)((u + 0x7FFFu + ((u >> 16) & 1u)) >> 16);
}
__device__ __forceinline__ float sigm(float z)  { return 1.0f / (1.0f + __expf(-z)); }
__device__ __forceinline__ float tanh_f(float z){ return 2.0f / (1.0f + __expf(-2.0f * z)) - 1.0f; }

__device__ __forceinline__ unsigned int aload(const unsigned int* p) {
    return __hip_atomic_load(p, __ATOMIC_RELAXED, __HIP_MEMORY_SCOPE_AGENT);
}
__device__ __forceinline__ void astore(unsigned int* p, unsigned int v) {
    __hip_atomic_store(p, v, __ATOMIC_RELAXED, __HIP_MEMORY_SCOPE_AGENT);
}
__device__ __forceinline__ void astore_s(unsigned short* p, unsigned short v) {
    __hip_atomic_store(p, v, __ATOMIC_RELAXED, __HIP_MEMORY_SCOPE_AGENT);
}

// Pack Wh [2048][8192] fp32 -> bf16 32x32x16 B-fragments.
// whp chunk = W*8192 + kh*4096 + kt*64 + lane (16 B units).
// Fragment: col = lane&31 -> (gate = col>>3, u = col&7), k = kh*1024 + kt*16
// + (lane>>5)*8 + j.  (k-octet convention cancels between A and B.)
__global__ void lstm_pack_kernel(const float* __restrict__ Wh,
                                 unsigned short* __restrict__ whp,
                                 unsigned short* __restrict__ hbufs,
                                 unsigned int* __restrict__ bar) {
    int chunk = blockIdx.x * 256 + threadIdx.x;     // 2,097,152 chunks total
    int lane = chunk & 63;
    int kt   = (chunk >> 6) & 63;
    int kh   = (chunk >> 12) & 1;
    int W    = chunk >> 13;
    int c    = lane & 31;
    int oct  = lane >> 5;
    int gate = c >> 3, u = c & 7;
    int n    = gate * 2048 + W * 8 + u;
    int k0   = kh * 1024 + kt * 16 + oct * 8;
    u16x8 frag;
    #pragma unroll
    for (int j = 0; j < 8; ++j)
        frag[j] = f2bf(Wh[(size_t)(k0 + j) * 8192 + n]);
    ((u16x8*)whp)[chunk] = frag;

    if (chunk < 32768) ((u32x4*)hbufs)[chunk] = (u32x4){0, 0, 0, 0};   // buf0: h(0)=0
    if (chunk < 2048) bar[chunk] = 0u;                                 // barrier words
}

// Contention-free monotonic tree barrier (phase = t+1, never reset). As R1.
__device__ __forceinline__ void grid_barrier(unsigned int* bar, unsigned int phase,
                                             bool do_inv, int W) {
    __syncthreads();   // drain h stores to the coherence point
    if (threadIdx.x < 64) {
        const int lane = threadIdx.x;
        if (lane == 0) astore(&bar[W], phase);                 // arrival
        if (W < 8) {
            unsigned int* sl = &bar[W * 32 + (lane & 31)];
            while (!__all((int)(aload(sl) >= phase)))
                __builtin_amdgcn_s_sleep(1);
            if (lane == 0) astore(&bar[512 + 16 * W], phase);  // done[W]
            if (W == 0) {
                unsigned int* dn = &bar[512 + 16 * (lane & 7)];
                while (!__all((int)(aload(dn) >= phase)))
                    __builtin_amdgcn_s_sleep(1);
                if (lane < 32) astore(&bar[1024 + 16 * lane], phase);  // broadcast
            }
        }
        if (lane == 0 && W != 0) {
            unsigned int* rl = &bar[1024 + 16 * (W & 31)];
            while (aload(rl) < phase)
                __builtin_amdgcn_s_sleep(1);
        }
        if (do_inv)
            __builtin_amdgcn_fence(__ATOMIC_ACQUIRE, "agent");   // buffer_inv (L1+L2)
    }
    __syncthreads();
}

__global__ __launch_bounds__(WG_THREADS, 2) void lstm_persist(
    const float* __restrict__ x,  const float* __restrict__ Wx,
    const float* __restrict__ b,  const float* __restrict__ Wph,
    const float* __restrict__ bp, const unsigned short* __restrict__ whp,
    unsigned short* hbufs, float* hfin,
    unsigned int* bar, float* out)
{
    extern __shared__ char lds[];
    const int tid = threadIdx.x;
    const int W   = blockIdx.x;

    // stage this WG's Wh slice (128 KB) into LDS (linear copy; layout matches pack)
    {
        const u32x4* src = (const u32x4*)whp + (size_t)W * 8192;
        u32x4* dst = (u32x4*)lds;
        for (int i = tid; i < 8192; i += WG_THREADS) dst[i] = src[i];
    }
    __syncthreads();

    const int lane = tid & 63;
    const int wv   = tid >> 6;
    const int wv2  = wv & 3;            // M-tile: rows 32*wv2 .. +31
    const int kh   = wv >> 2;           // K-half: k in [kh*1024, kh*1024+1024)
    const int l31  = lane & 31;
    const int oct  = lane >> 5;         // k-octet within fragment
    const int u    = lane & 7;          // hidden unit within slice
    const int gamma= (lane >> 3) & 3;   // gate index of this lane's column

    // gate-wise Wx/bias scalars for this lane's unit (INPUT_DIM = 1)
    const int nbase = W * 8 + u;
    float wxg[4], bbg[4];
    #pragma unroll
    for (int g = 0; g < 4; ++g) {
        wxg[g] = Wx[g * 2048 + nbase];
        bbg[g] = b[g * 2048 + nbase];
    }

    // A-fragment (32x32x16): row = lane&31 (within M-tile), k-octet = oct.
    // h layout h[kblk][row][8]: x8-index = (kh*128 + kt*2 + oct)*128 +
    // 32*wv2 + (lane&31); per-kt stride 256.
    const int abase = kh * 16384 + oct * 128 + 32 * wv2 + l31;
    // B-fragment LDS base: (kh*64 + kt)*1024 + lane*16 bytes
    const char* lpB0 = lds + kh * 65536 + lane * 16;

    char* redp = lds + RED_OFF + (size_t)(wv2 * 64 + lane) * RED_STRIDE;

    const int g0 = gamma & 1, g1 = (gamma >> 1) & 1;
    float c_state[4] = {0.f, 0.f, 0.f, 0.f};   // meaningful on kh==0 waves

    for (int t = 0; t < STEPS; ++t) {
        unsigned short* hcur  = hbufs + (size_t)(t & 3) * 262144;        // elements
        unsigned short* hnext = hbufs + (size_t)((t + 1) & 3) * 262144;
        const bf16x8* hc8 = (const bf16x8*)hcur;

        // xv preload (only consumer waves need it)
        float xva[4];
        if (kh == 0) {
            #pragma unroll
            for (int a = 0; a < 4; ++a) {
                int row = 32 * wv2 + gamma + 8 * a + 4 * oct;
                xva[a] = x[row * SEQ_LEN + t];
            }
        }

        // 16-deep rotating register prefetch of A fragments
        bf16x8 a_pf[PF];
        #pragma unroll
        for (int i = 0; i < PF; ++i)
            a_pf[i] = hc8[abase + i * 256];

        f32x16 acc = {0.f};
        // phase A (kt 0..47): prefetch kt+PF always valid (tail-split, R8)
        #pragma unroll 16
        for (int kt = 0; kt < KTILES - PF; ++kt) {
            bf16x8 a_cur = a_pf[kt & (PF - 1)];
            a_pf[kt & (PF - 1)] = hc8[abase + (kt + PF) * 256];
            bf16x8 bb = *(const bf16x8*)(lpB0 + kt * 1024);
            acc = __builtin_amdgcn_mfma_f32_32x32x16_bf16(a_cur, bb, acc, 0, 0, 0);
        }
        // phase B (kt 48..63): consume a_pf, no prefetch
        #pragma unroll
        for (int i = 0; i < PF; ++i) {
            bf16x8 bb = *(const bf16x8*)(lpB0 + ((KTILES - PF) + i) * 1024);
            acc = __builtin_amdgcn_mfma_f32_32x32x16_bf16(a_pf[i], bb, acc, 0, 0, 0);
        }

        // ---- K-half reduction through LDS (kh=1 writes, kh=0 adds) ----
        if (kh == 1) {
            #pragma unroll
            for (int j = 0; j < 8; ++j) {
                float2 v; v.x = acc[2 * j]; v.y = acc[2 * j + 1];
                *(float2*)(redp + 8 * j) = v;
            }
        }
        __syncthreads();

        const bool last = (t == STEPS - 1);
        if (kh == 0) {
            #pragma unroll
            for (int j = 0; j < 8; ++j) {
                float2 v = *(const float2*)(redp + 8 * j);
                acc[2 * j] += v.x; acc[2 * j + 1] += v.y;
            }
            // C/D layout: col = lane&31, row = (reg&3) + 8*(reg>>2) + 4*oct.
            // xor-gather: lane gamma of each 8-group finishes reg 4a+gamma,
            // so all 64 lanes do gate math (3 shuffles + selects per quad).
            #pragma unroll
            for (int a = 0; a < 4; ++a) {
                float q0 = acc[4 * a + 0], q1 = acc[4 * a + 1];
                float q2 = acc[4 * a + 2], q3 = acc[4 * a + 3];
                float s1  = g0 ? (g1 ? q2 : q0) : (g1 ? q3 : q1);   // acc[4a+(γ^1)]
                float s2  = g1 ? (g0 ? q1 : q0) : (g0 ? q3 : q2);   // acc[4a+(γ^2)]
                float s3  = g1 ? (g0 ? q0 : q1) : (g0 ? q2 : q3);   // acc[4a+(γ^3)]
                float own = g1 ? (g0 ? q3 : q2) : (g0 ? q1 : q0);   // acc[4a+γ]
                float r1 = __shfl_xor(s1, 8, 64);
                float r2 = __shfl_xor(s2, 16, 64);
                float r3 = __shfl_xor(s3, 24, 64);
                float zg = g1 ? (g0 ? r3 : r2) : (g0 ? r1 : own);
                float zi = g1 ? (g0 ? r2 : r3) : (g0 ? own : r1);
                float zf = g1 ? (g0 ? r1 : own) : (g0 ? r3 : r2);
                float zo = g1 ? (g0 ? own : r1) : (g0 ? r2 : r3);
                zg += xva[a] * wxg[0] + bbg[0];
                zi += xva[a] * wxg[1] + bbg[1];
                zf += xva[a] * wxg[2] + bbg[2];
                zo += xva[a] * wxg[3] + bbg[3];
                float cn = tanh_f(zg) * sigm(zi) + c_state[a] * sigm(zf);
                c_state[a] = cn;
                float h = tanh_f(cn) * sigm(zo);
                int row = 32 * wv2 + gamma + 8 * a + 4 * oct;
                // direct coalesced h-write: for fixed a, the wave's 64 lanes
                // cover bytes (gamma+4*oct)*16 + u*2 + 128*a + 512*wv2 of the
                // W-block = 2 full 64B lines per store instruction (R5-safe).
                astore_s(&hnext[W * 1024 + row * 8 + u], f2bf(h));
                if (last)
                    __hip_atomic_store(&hfin[row * HIDDEN + W * 8 + u], h,
                                       __ATOMIC_RELAXED, __HIP_MEMORY_SCOPE_AGENT);
            }
        }
        // stores drain under the barrier's first __syncthreads, then arrival.
        // inv every 4th barrier (stale L2 age <= 4 with the 4-buffer rotation);
        // t==254 (phase 2) also covers the hfin handoff to the cached epilogue.
        grid_barrier(bar, (unsigned int)(t + 1), (t & 3) == 2 || last, W);
    }

    // ---- classifier + softmax epilogue: WG b handles batch row b ----
    if (W < BATCH) {
        float part[CLASSES];
        #pragma unroll
        for (int c = 0; c < CLASSES; ++c) part[c] = 0.f;
        for (int k = tid; k < HIDDEN; k += WG_THREADS) {
            float hv = hfin[W * HIDDEN + k];
            #pragma unroll
            for (int c = 0; c < CLASSES; ++c) part[c] += hv * Wph[k * CLASSES + c];
        }
        #pragma unroll
        for (int c = 0; c < CLASSES; ++c)
            for (int off = 32; off > 0; off >>= 1)
                part[c] += __shfl_xor(part[c], off, 64);
        float* red = (float*)(lds + RED_OFF);
        __syncthreads();
        const int wvq = tid >> 6;
        if ((tid & 63) == 0)
            for (int c = 0; c < CLASSES; ++c) red[wvq * CLASSES + c] = part[c];
        __syncthreads();
        if (tid == 0) {
            float lg[CLASSES];
            for (int c = 0; c < CLASSES; ++c) {
                float sm = bp[c];
                for (int w8 = 0; w8 < 8; ++w8) sm += red[w8 * CLASSES + c];
                lg[c] = sm;
            }
            float mx = lg[0];
            for (int c = 1; c < CLASSES; ++c) mx = fmaxf(mx, lg[c]);
            float se = 0.f;
            for (int c = 0; c < CLASSES; ++c) { lg[c] = __expf(lg[c] - mx); se += lg[c]; }
            float inv = 1.0f / se;
            for (int c = 0; c < CLASSES; ++c) out[W * CLASSES + c] = lg[c] * inv;
        }
    }
}

extern "C" void kernel_launch(void* const* d_in, const int* in_sizes, int n_in,
                              void* d_out, int out_size, void* d_ws, size_t ws_size,
                              hipStream_t stream) {
    const float* x   = (const float*)d_in[0];
    const float* Wx  = (const float*)d_in[1];
    const float* Wh  = (const float*)d_in[2];
    const float* b   = (const float*)d_in[3];
    const float* Wph = (const float*)d_in[4];
    const float* bp  = (const float*)d_in[5];
    float* out = (float*)d_out;

    char* ws = (char*)d_ws;
    unsigned short* whp  = (unsigned short*)(ws + WHP_OFF);
    unsigned short* hbufs= (unsigned short*)(ws + HB_OFF);
    float*          hfin = (float*)(ws + HF_OFF);
    unsigned int*   bar  = (unsigned int*)(ws + BAR_OFF);

    hipFuncSetAttribute((const void*)lstm_persist,
                        hipFuncAttributeMaxDynamicSharedMemorySize, LDS_ALL);

    lstm_pack_kernel<<<8192, 256, 0, stream>>>(Wh, whp, hbufs, bar);
    lstm_persist<<<NWG, WG_THREADS, LDS_ALL, stream>>>(x, Wx, b, Wph, bp,
                                                       whp, hbufs, hfin, bar, out);
}